// Round 4
// baseline (613.621 us; speedup 1.0000x reference)
//
#include <hip/hip_runtime.h>
#include <math.h>

#define Cc     8
#define PAD    3
#define TW     32        // tile width
#define TH     16        // tile height
#define HAW    38        // TW + 6 halo width
#define HAH    22        // TH + 6 halo height
#define QSTR   38        // qs row stride (uint4); A-reads are uniform-per-row -> no pad needed
#define PRS    33        // pen row stride (dwords)
#define PPL    533       // pen plane stride (dwords) = 16*33 + 5; 533%32=21 spreads scatter banks
#define BB     32
#define HH     384
#define WW     384
#define NS     35        // MFMAs per wave: 70 slots (10 dy' x 7 dx) / 2 per K=16
#define UCLIP  13.815510557964274f   // -log(1e-6)

typedef __attribute__((ext_vector_type(8)))  short short8;   // 8 bf16 = 4 VGPRs
typedef __attribute__((ext_vector_type(16))) float f32x16;   // 32x32 MFMA C/D

__device__ __forceinline__ unsigned short f2bf(float f) {   // RNE fp32->bf16
    unsigned u = __float_as_uint(f);
    u += 0x7FFFu + ((u >> 16) & 1u);
    return (unsigned short)(u >> 16);
}

// ---------------------------------------------------------------------------
// prep_w: COMPACT fused weight table W2[t][d][j], t in [0,51):
//   W2[t][d][j] = (1<=t<=49) ? sum_c kw[t-1][j][c]*(c!=j)*sw[c][d] : 0
// (7x7 conv fused with 1x1 k_scale; off-diagonal mask on (cin=j, cout=c)).
// t=0 and t=50 are zero-pads so the kernel can clamp out-of-range taps.
// 51*8*8*2B = 6528 B -> permanently L1-resident.
// ---------------------------------------------------------------------------
__global__ __launch_bounds__(256)
void prep_w(const float* __restrict__ kw, const float* __restrict__ sw,
            unsigned short* __restrict__ wtab) {
    int it = blockIdx.x * 256 + threadIdx.x;      // (t, d)
    if (it >= 51 * 8) return;
    int t = it >> 3, d = it & 7;
#pragma unroll
    for (int j = 0; j < 8; ++j) {
        float a = 0.f;
        if (t >= 1 && t <= 49) {
            int tap = t - 1;
#pragma unroll
            for (int c = 0; c < 8; ++c) {
                float kv = (c == j) ? 0.f : kw[(tap * 8 + j) * 8 + c];
                a = fmaf(kv, sw[c * 8 + d], a);
            }
        }
        wtab[(t * 8 + d) * 8 + j] = f2bf(a);
    }
}

// ---------------------------------------------------------------------------
// init_qv: q0 = softmax(x) packed bf16x8; v = b - u@W  (u = min(lse-x, UCLIP))
// ---------------------------------------------------------------------------
__global__ __launch_bounds__(256)
void init_qv(const float* __restrict__ x, const float* __restrict__ sw,
             const float* __restrict__ sb,
             uint4* __restrict__ q0, float* __restrict__ v) {
    long long p = (long long)blockIdx.x * 256 + threadIdx.x;
    const float4* xp = (const float4*)(x + p * Cc);
    float4 a0 = xp[0], a1 = xp[1];
    float xv[Cc] = {a0.x, a0.y, a0.z, a0.w, a1.x, a1.y, a1.z, a1.w};
    float m = xv[0];
#pragma unroll
    for (int c = 1; c < Cc; ++c) m = fmaxf(m, xv[c]);
    float s = 0.f, e[Cc];
#pragma unroll
    for (int c = 0; c < Cc; ++c) { e[c] = __expf(xv[c] - m); s += e[c]; }
    float inv = 1.f / s;
    uint4 qo;
    qo.x = f2bf(e[0] * inv) | ((unsigned)f2bf(e[1] * inv) << 16);
    qo.y = f2bf(e[2] * inv) | ((unsigned)f2bf(e[3] * inv) << 16);
    qo.z = f2bf(e[4] * inv) | ((unsigned)f2bf(e[5] * inv) << 16);
    qo.w = f2bf(e[6] * inv) | ((unsigned)f2bf(e[7] * inv) << 16);
    q0[p] = qo;

    float lse = m + __logf(s);
    float u[Cc];
#pragma unroll
    for (int c = 0; c < Cc; ++c) u[c] = fminf(lse - xv[c], UCLIP);
    float vv[Cc];
#pragma unroll
    for (int d = 0; d < Cc; ++d) {
        float a = sb[d];
#pragma unroll
        for (int c = 0; c < Cc; ++c) a = fmaf(-u[c], sw[c * Cc + d], a);
        vv[d] = a;
    }
    float4* vp = (float4*)(v + p * Cc);
    vp[0] = make_float4(vv[0], vv[1], vv[2], vv[3]);
    vp[1] = make_float4(vv[4], vv[5], vv[6], vv[7]);
}

// ---------------------------------------------------------------------------
// mrf_iter: logits = v - conv7x7(q, k'); out = softmax(logits) bf16 (or
// logits fp32 on the last iteration).
// Conv via mfma_f32_32x32x16_bf16 with 4-ROW N-packing:
//   M = 32 px (tile width), N = 32 = 4 output rows x 8 channels,
//   K = 16 = 2 slots x 8 cin;  slot sigma = 2S + (lane>>5), sigma = dy'*7+dx,
//   dy' in [0,10). Input row (4wv + dy') feeds output rows 4wv+rn with tap
//   sigma - 7rn (clamped into the zero-padded compact table).
// A from LDS (lane-uniform per row -> conflict-free); B streamed from the
// 6.5KB L1-resident table (TA/L1 pipe runs parallel to LDS pipe).
// Block = 256 = 4 waves; wave wv owns output rows 4wv..4wv+3 x 32 px.
// ---------------------------------------------------------------------------
__global__ __launch_bounds__(256)
void mrf_iter(const uint4* __restrict__ qin,          // bf16x8 per pixel
              const unsigned short* __restrict__ wtab,
              const float* __restrict__ v,            // fp32, 8 per pixel
              uint4* __restrict__ qout,               // next q (bf16) if !last
              float* __restrict__ lout,               // logits fp32 if last
              int last) {
    __shared__ __align__(16) uint4 qs[HAH * QSTR];      // 13376 B
    __shared__ __align__(16) float pen[Cc * PPL];       // 17056 B

    const int tid = threadIdx.x;
    const int wv  = tid >> 6;        // wave 0..3
    const int l   = tid & 63;
    const int m32 = l & 31;          // A-row = px; also D col n
    const int hi  = l >> 5;          // K half: slot parity
    const int rn  = m32 >> 3;        // D: output row offset 0..3
    const int dch = m32 & 7;         // D: output channel

    const int w0 = blockIdx.x * TW;
    const int h0 = blockIdx.y * TH;
    const int b  = blockIdx.z;

    // --- hoisted epilogue v loads: 2 px per thread ---
    const int ey = tid >> 4;             // 0..15
    const int ex = (tid & 15) * 2;       // 0..30 step 2
    const long long pixbase = ((long long)b * HH + (h0 + ey)) * WW + (w0 + ex);
    const float4* vp = (const float4*)(v + pixbase * Cc);
    float4 va0 = vp[0], va1 = vp[1], vb0 = vp[2], vb1 = vp[3];

    // --- stage q tile + halo (bf16x8 per pixel, zero-pad = SAME) ---
    const uint4* qb = qin + (long long)b * HH * WW;
    for (int s = tid; s < HAH * HAW; s += 256) {
        int sy = s / HAW, sx = s - sy * HAW;
        int gh = h0 + sy - PAD, gw = w0 + sx - PAD;
        uint4 val = make_uint4(0, 0, 0, 0);
        if (gh >= 0 && gh < HH && gw >= 0 && gw < WW)
            val = qb[(long long)gh * WW + gw];
        qs[sy * QSTR + sx] = val;
    }
    __syncthreads();

    // --- K loop: 35 MFMAs, slots sigma = 2S + hi ---
    f32x16 accA = (f32x16){0.f,0.f,0.f,0.f,0.f,0.f,0.f,0.f,
                           0.f,0.f,0.f,0.f,0.f,0.f,0.f,0.f};
    f32x16 accB = accA;
    const int base0 = 4 * wv * QSTR + m32;   // qs row 4wv, col m32
    const int hi1   = hi;                    // sigma-odd delta when dxE < 6
    const int hiQ   = hi << 5;               // delta QSTR-6 = 32 when dxE == 6
    const int c0    = hi - 7 * rn + 1;       // table idx = 2S + c0, clamp [0,50]
    const unsigned short* Wd = wtab + dch * 8;

#pragma unroll
    for (int S = 0; S < NS; ++S) {
        const int sE  = 2 * S;
        const int dyE = sE / 7, dxE = sE % 7;            // compile-time
        const int off = base0 + dyE * QSTR + dxE + ((dxE == 6) ? hiQ : hi1);
        short8 a = *(const short8*)&qs[off];
        int t_ = 2 * S + c0;
        t_ = t_ < 0 ? 0 : (t_ > 50 ? 50 : t_);
        short8 bw = *(const short8*)(Wd + t_ * 64);      // L1-hot, 128B/8-lane grp
        if (S & 1) accB = __builtin_amdgcn_mfma_f32_32x32x16_bf16(a, bw, accB, 0, 0, 0);
        else       accA = __builtin_amdgcn_mfma_f32_32x32x16_bf16(a, bw, accA, 0, 0, 0);
    }
    f32x16 acc = accA + accB;

    // --- scatter D: lane holds D[m=(t&3)+8(t>>2)+4hi][n=8rn+dch] ---
    {
        const int pbase = dch * PPL + (4 * wv + rn) * PRS + 4 * hi;
#pragma unroll
        for (int t = 0; t < 16; ++t) {
            int mpx = (t & 3) + 8 * (t >> 2);
            pen[pbase + mpx] = acc[t];
        }
    }
    __syncthreads();

    // --- epilogue: 2 px per thread ---
    float o0[Cc], o1[Cc];
#pragma unroll
    for (int c = 0; c < Cc; ++c) {
        o0[c] = pen[c * PPL + ey * PRS + ex];
        o1[c] = pen[c * PPL + ey * PRS + ex + 1];
    }
    o0[0] = va0.x - o0[0]; o0[1] = va0.y - o0[1]; o0[2] = va0.z - o0[2]; o0[3] = va0.w - o0[3];
    o0[4] = va1.x - o0[4]; o0[5] = va1.y - o0[5]; o0[6] = va1.z - o0[6]; o0[7] = va1.w - o0[7];
    o1[0] = vb0.x - o1[0]; o1[1] = vb0.y - o1[1]; o1[2] = vb0.z - o1[2]; o1[3] = vb0.w - o1[3];
    o1[4] = vb1.x - o1[4]; o1[5] = vb1.y - o1[5]; o1[6] = vb1.z - o1[6]; o1[7] = vb1.w - o1[7];

    if (last) {
        float4* op = (float4*)(lout + pixbase * Cc);
        op[0] = make_float4(o0[0], o0[1], o0[2], o0[3]);
        op[1] = make_float4(o0[4], o0[5], o0[6], o0[7]);
        op[2] = make_float4(o1[0], o1[1], o1[2], o1[3]);
        op[3] = make_float4(o1[4], o1[5], o1[6], o1[7]);
    } else {
        float mm0 = o0[0], mm1 = o1[0];
#pragma unroll
        for (int d = 1; d < Cc; ++d) { mm0 = fmaxf(mm0, o0[d]); mm1 = fmaxf(mm1, o1[d]); }
        float s0 = 0.f, s1 = 0.f, e0[Cc], e1[Cc];
#pragma unroll
        for (int d = 0; d < Cc; ++d) {
            e0[d] = __expf(o0[d] - mm0); s0 += e0[d];
            e1[d] = __expf(o1[d] - mm1); s1 += e1[d];
        }
        float i0 = 1.f / s0, i1 = 1.f / s1;
        uint4 qo0, qo1;
        qo0.x = f2bf(e0[0] * i0) | ((unsigned)f2bf(e0[1] * i0) << 16);
        qo0.y = f2bf(e0[2] * i0) | ((unsigned)f2bf(e0[3] * i0) << 16);
        qo0.z = f2bf(e0[4] * i0) | ((unsigned)f2bf(e0[5] * i0) << 16);
        qo0.w = f2bf(e0[6] * i0) | ((unsigned)f2bf(e0[7] * i0) << 16);
        qo1.x = f2bf(e1[0] * i1) | ((unsigned)f2bf(e1[1] * i1) << 16);
        qo1.y = f2bf(e1[2] * i1) | ((unsigned)f2bf(e1[3] * i1) << 16);
        qo1.z = f2bf(e1[4] * i1) | ((unsigned)f2bf(e1[5] * i1) << 16);
        qo1.w = f2bf(e1[6] * i1) | ((unsigned)f2bf(e1[7] * i1) << 16);
        qout[pixbase]     = qo0;
        qout[pixbase + 1] = qo1;
    }
}

extern "C" void kernel_launch(void* const* d_in, const int* in_sizes, int n_in,
                              void* d_out, int out_size, void* d_ws, size_t ws_size,
                              hipStream_t stream) {
    (void)in_sizes; (void)n_in; (void)out_size; (void)ws_size;
    const float* x  = (const float*)d_in[0];   // [32,384,384,8]
    const float* kw = (const float*)d_in[1];   // [7,7,8,8]
    const float* sw = (const float*)d_in[2];   // [8,8]
    const float* sb = (const float*)d_in[3];   // [8]

    const size_t QSZ = (size_t)BB * HH * WW * 16;        // 75,497,472 B (bf16x8)
    uint4* qA = (uint4*)d_ws;
    uint4* qB = (uint4*)((char*)d_ws + QSZ);
    unsigned short* wt = (unsigned short*)((char*)d_ws + 2 * QSZ);  // 6528 B
    float* vbuf = (float*)d_out;   // v lives in d_out; last iter overwrites in place

    prep_w<<<2, 256, 0, stream>>>(kw, sw, wt);

    const long long npix = (long long)BB * HH * WW;
    init_qv<<<(int)(npix / 256), 256, 0, stream>>>(x, sw, sb, qA, vbuf);

    dim3 grid(WW / TW, HH / TH, BB);   // 12 x 24 x 32
    mrf_iter<<<grid, 256, 0, stream>>>(qA, wt, vbuf, qB, nullptr, 0);
    mrf_iter<<<grid, 256, 0, stream>>>(qB, wt, vbuf, qA, nullptr, 0);
    mrf_iter<<<grid, 256, 0, stream>>>(qA, wt, vbuf, qB, nullptr, 0);
    mrf_iter<<<grid, 256, 0, stream>>>(qB, wt, vbuf, qA, nullptr, 0);
    mrf_iter<<<grid, 256, 0, stream>>>(qA, wt, vbuf, nullptr, (float*)d_out, 1);
}

// Round 5
// 542.417 us; speedup vs baseline: 1.1313x; 1.1313x over previous
//
#include <hip/hip_runtime.h>
#include <math.h>

#define Cc     8
#define FIELD  7
#define PAD    3
#define TW     32        // tile width
#define TH     16        // tile height
#define HAW    38        // TW + 6
#define HAH    22        // TH + 6
#define QSTR   39        // qs row stride (uint4): dRow=2 K-group offsets -> residues {0,24,16,8}
#define BB     32
#define HH     384
#define WW     384
#define NSLOT  56        // 8 dy' x 7 dx slots for a row-PAIR
#define NG     14        // 56/4 K-groups; slot = 14*g + S
#define UCLIP  13.815510557964274f   // -log(1e-6)

typedef __attribute__((ext_vector_type(8))) short short8;  // 8 bf16 = 4 VGPRs
typedef __attribute__((ext_vector_type(4))) float f32x4;   // MFMA C/D

__device__ __forceinline__ unsigned short f2bf(float f) {   // RNE fp32->bf16
    unsigned u = __float_as_uint(f);
    u += 0x7FFFu + ((u >> 16) & 1u);
    return (unsigned short)(u >> 16);
}

// ---------------------------------------------------------------------------
// prep_w: row-pair fused weight table (IDENTICAL to the R2-verified version).
// Slot s = dy'*7 + dx, dy' in [0,8), dx in [0,7). For n = 8h + d:
//   wtab[s][n][j] = W[(dy'-h)*7+dx][j][d] if 0 <= dy'-h < 7 else 0,
// W[tap][j][d] = sum_c kw[tap][j][c]*(c!=j)*sw[c][d].
// Read as the MFMA *A* operand now: lane field (l&15) indexes n = 8h+d.
// ---------------------------------------------------------------------------
__global__ __launch_bounds__(256)
void prep_w(const float* __restrict__ kw, const float* __restrict__ sw,
            unsigned short* __restrict__ wtab) {
    int it = blockIdx.x * 256 + threadIdx.x;      // (slot, j=cin)
    if (it >= NSLOT * 8) return;
    int s = it >> 3, j = it & 7;
    int dyp = s / 7, dx = s - dyp * 7;
#pragma unroll
    for (int n = 0; n < 16; ++n) {
        int h = n >> 3, d = n & 7;
        int dy = dyp - h;
        float a = 0.f;
        if (dy >= 0 && dy < FIELD) {
            int tap = dy * 7 + dx;
#pragma unroll
            for (int c = 0; c < Cc; ++c) {
                float kv = (c == j) ? 0.f : kw[(tap * Cc + j) * Cc + c];
                a = fmaf(kv, sw[c * Cc + d], a);
            }
        }
        wtab[(s * 16 + n) * 8 + j] = f2bf(a);
    }
}

// ---------------------------------------------------------------------------
// init_qv: q0 = softmax(x) packed bf16x8; v = b - u@W  (u = min(lse-x, UCLIP))
// ---------------------------------------------------------------------------
__global__ __launch_bounds__(256)
void init_qv(const float* __restrict__ x, const float* __restrict__ sw,
             const float* __restrict__ sb,
             uint4* __restrict__ q0, float* __restrict__ v) {
    long long p = (long long)blockIdx.x * 256 + threadIdx.x;
    const float4* xp = (const float4*)(x + p * Cc);
    float4 a0 = xp[0], a1 = xp[1];
    float xv[Cc] = {a0.x, a0.y, a0.z, a0.w, a1.x, a1.y, a1.z, a1.w};
    float m = xv[0];
#pragma unroll
    for (int c = 1; c < Cc; ++c) m = fmaxf(m, xv[c]);
    float s = 0.f, e[Cc];
#pragma unroll
    for (int c = 0; c < Cc; ++c) { e[c] = __expf(xv[c] - m); s += e[c]; }
    float inv = 1.f / s;
    uint4 qo;
    qo.x = f2bf(e[0] * inv) | ((unsigned)f2bf(e[1] * inv) << 16);
    qo.y = f2bf(e[2] * inv) | ((unsigned)f2bf(e[3] * inv) << 16);
    qo.z = f2bf(e[4] * inv) | ((unsigned)f2bf(e[5] * inv) << 16);
    qo.w = f2bf(e[6] * inv) | ((unsigned)f2bf(e[7] * inv) << 16);
    q0[p] = qo;

    float lse = m + __logf(s);
    float u[Cc];
#pragma unroll
    for (int c = 0; c < Cc; ++c) u[c] = fminf(lse - xv[c], UCLIP);
    float vv[Cc];
#pragma unroll
    for (int d = 0; d < Cc; ++d) {
        float a = sb[d];
#pragma unroll
        for (int c = 0; c < Cc; ++c) a = fmaf(-u[c], sw[c * Cc + d], a);
        vv[d] = a;
    }
    float4* vp = (float4*)(v + p * Cc);
    vp[0] = make_float4(vv[0], vv[1], vv[2], vv[3]);
    vp[1] = make_float4(vv[4], vv[5], vv[6], vv[7]);
}

// ---------------------------------------------------------------------------
// mrf_iter: logits = v - conv7x7(q, k'); out = softmax(logits) bf16 (or
// logits fp32 on the last iteration).
// OPERAND-SWAPPED row-pair MFMA conv (mfma_f32_16x16x32_bf16):
//   A = weights (M = 16 = 2 rows x 8 ch), B = q pixels (N = 16 px),
//   K = 32 = 4 slots x 8 cin; slot = 14g + S, dy' = 2g+(S>=7), dx = S%7.
// D: lane l holds D[4g+t][l&15] = channel-quad 4(g&1)+t of row-half g>>1,
// pixel px=l&15 -- so ONE shfl_xor(16) per reg gives each lane a full
// 8-channel pixel: softmax entirely in registers, NO pen LDS, NO 2nd barrier.
// Block = 512 thr = 8 waves; wave w: rows 4(w>>1).., col-half 16(w&1).
// ---------------------------------------------------------------------------
__global__ __launch_bounds__(512)
void mrf_iter(const uint4* __restrict__ qin,          // bf16x8 per pixel
              const unsigned short* __restrict__ wtab,
              const float* __restrict__ v,            // fp32, 8 per pixel
              uint4* __restrict__ qout,               // next q (bf16) if !last
              float* __restrict__ lout,               // logits fp32 if last
              int last) {
    __shared__ __align__(16) uint4 qs[HAH * QSTR];      // 22*39*16 = 13728 B

    const int tid = threadIdx.x;
    const int wv  = tid >> 6;        // wave 0..7
    const int l   = tid & 63;
    const int m   = l & 15;          // A-lane field (weight n) AND D col (pixel)
    const int g   = l >> 4;          // K-group

    const int w0 = blockIdx.x * TW;
    const int h0 = blockIdx.y * TH;
    const int b  = blockIdx.z;

    const int r0 = 4 * (wv >> 1);    // wave's top output row
    const int cx = 16 * (wv & 1);    // wave's column half

    // --- this lane's output pixel (fixed): pair p=g&1, half h=g>>1 ---
    const int p   = g & 1;
    const int row = r0 + 2 * p + (g >> 1);
    const int px  = cx + m;
    const long long pix = ((long long)b * HH + (h0 + row)) * WW + (w0 + px);

    // --- hoisted v load for this pixel (latency hiding; block-private alias) ---
    const float4* vp = (const float4*)(v + pix * Cc);
    float4 v0 = vp[0], v1 = vp[1];

    // --- A fragments (weights): 14 x (8 bf16), L2-hot, VGPR-resident ---
    short8 bw[NG];
#pragma unroll
    for (int S = 0; S < NG; ++S) {
        uint4 t = *(const uint4*)(wtab + ((g * NG + S) * 16 + m) * 8);
        bw[S] = __builtin_bit_cast(short8, t);
    }

    // --- stage q tile + halo (bf16x8 per pixel, zero-pad = SAME) ---
    const uint4* qb = qin + (long long)b * HH * WW;
    for (int s = tid; s < HAH * HAW; s += 512) {
        int sy = s / HAW, sx = s - sy * HAW;
        int gh = h0 + sy - PAD, gw = w0 + sx - PAD;
        uint4 val = make_uint4(0, 0, 0, 0);
        if (gh >= 0 && gh < HH && gw >= 0 && gw < WW)
            val = qs[0].x ? val : val;  // no-op to keep structure simple
        if (gh >= 0 && gh < HH && gw >= 0 && gw < WW)
            val = qb[(long long)gh * WW + gw];
        qs[sy * QSTR + sx] = val;
    }
    __syncthreads();

    // --- K loop: 14 groups x 2 pairs; q row = r0 + 2g + (S>=7) (+2 for pair1) ---
    f32x4 acc0 = (f32x4){0.f, 0.f, 0.f, 0.f};
    f32x4 acc1 = (f32x4){0.f, 0.f, 0.f, 0.f};
    const int base = (r0 + 2 * g) * QSTR + cx + m;
#pragma unroll
    for (int S = 0; S < NG; ++S) {
        const int off = base + ((S >= 7) ? QSTR : 0) + (S % 7);
        short8 q0 = *(const short8*)&qs[off];
        acc0 = __builtin_amdgcn_mfma_f32_16x16x32_bf16(bw[S], q0, acc0, 0, 0, 0);
        short8 q1 = *(const short8*)&qs[off + 2 * QSTR];
        acc1 = __builtin_amdgcn_mfma_f32_16x16x32_bf16(bw[S], q1, acc1, 0, 0, 0);
    }

    // --- in-register transpose: partner lane (l^16) has the other quad ---
    // lane holds channels 4p+t of its assigned pair p in acc_p[t]
    float o[Cc];
#pragma unroll
    for (int t = 0; t < 4; ++t) {
        float s0 = __shfl_xor(acc0[t], 16);
        float s1 = __shfl_xor(acc1[t], 16);
        o[t]     = p ? s1        : acc0[t];   // channels 0..3
        o[4 + t] = p ? acc1[t]   : s0;        // channels 4..7
    }

    // --- epilogue (fully in registers) ---
    o[0] = v0.x - o[0]; o[1] = v0.y - o[1]; o[2] = v0.z - o[2]; o[3] = v0.w - o[3];
    o[4] = v1.x - o[4]; o[5] = v1.y - o[5]; o[6] = v1.z - o[6]; o[7] = v1.w - o[7];
    if (last) {
        float4* op = (float4*)(lout + pix * Cc);
        op[0] = make_float4(o[0], o[1], o[2], o[3]);
        op[1] = make_float4(o[4], o[5], o[6], o[7]);
    } else {
        float mm = o[0];
#pragma unroll
        for (int d = 1; d < Cc; ++d) mm = fmaxf(mm, o[d]);
        float ss = 0.f, e[Cc];
#pragma unroll
        for (int d = 0; d < Cc; ++d) { e[d] = __expf(o[d] - mm); ss += e[d]; }
        float inv = 1.f / ss;
        uint4 qo;
        qo.x = f2bf(e[0] * inv) | ((unsigned)f2bf(e[1] * inv) << 16);
        qo.y = f2bf(e[2] * inv) | ((unsigned)f2bf(e[3] * inv) << 16);
        qo.z = f2bf(e[4] * inv) | ((unsigned)f2bf(e[5] * inv) << 16);
        qo.w = f2bf(e[6] * inv) | ((unsigned)f2bf(e[7] * inv) << 16);
        qout[pix] = qo;
    }
}

extern "C" void kernel_launch(void* const* d_in, const int* in_sizes, int n_in,
                              void* d_out, int out_size, void* d_ws, size_t ws_size,
                              hipStream_t stream) {
    (void)in_sizes; (void)n_in; (void)out_size; (void)ws_size;
    const float* x  = (const float*)d_in[0];   // [32,384,384,8]
    const float* kw = (const float*)d_in[1];   // [7,7,8,8]
    const float* sw = (const float*)d_in[2];   // [8,8]
    const float* sb = (const float*)d_in[3];   // [8]

    const size_t QSZ = (size_t)BB * HH * WW * 16;        // 75,497,472 B (bf16x8)
    uint4* qA = (uint4*)d_ws;
    uint4* qB = (uint4*)((char*)d_ws + QSZ);
    unsigned short* wt = (unsigned short*)((char*)d_ws + 2 * QSZ);  // 14336 B
    float* vbuf = (float*)d_out;   // v lives in d_out; last iter overwrites in place

    prep_w<<<2, 256, 0, stream>>>(kw, sw, wt);

    const long long npix = (long long)BB * HH * WW;
    init_qv<<<(int)(npix / 256), 256, 0, stream>>>(x, sw, sb, qA, vbuf);

    dim3 grid(WW / TW, HH / TH, BB);   // 12 x 24 x 32
    mrf_iter<<<grid, 512, 0, stream>>>(qA, wt, vbuf, qB, nullptr, 0);
    mrf_iter<<<grid, 512, 0, stream>>>(qB, wt, vbuf, qA, nullptr, 0);
    mrf_iter<<<grid, 512, 0, stream>>>(qA, wt, vbuf, qB, nullptr, 0);
    mrf_iter<<<grid, 512, 0, stream>>>(qB, wt, vbuf, qA, nullptr, 0);
    mrf_iter<<<grid, 512, 0, stream>>>(qA, wt, vbuf, nullptr, (float*)d_out, 1);
}

// Round 6
// 527.531 us; speedup vs baseline: 1.1632x; 1.0282x over previous
//
#include <hip/hip_runtime.h>
#include <math.h>

#define Cc     8
#define FIELD  7
#define PAD    3
#define TW     32        // tile width
#define TH     16        // tile height
#define HAW    38        // TW + 6
#define HAH    22        // TH + 6
#define QSTR   39        // qs row stride (uint4); col 38 = pad col (staged, zero weight)
#define BB     32
#define HH     384
#define WW     384
#define NSLOT  64        // 8 dy' x 8 dx slots (dx==7 zero-pad) for a row-PAIR
#define UCLIP  13.815510557964274f   // -log(1e-6)

typedef __attribute__((ext_vector_type(8))) short short8;  // 8 bf16 = 4 VGPRs
typedef __attribute__((ext_vector_type(4))) float f32x4;   // MFMA C/D

__device__ __forceinline__ unsigned short f2bf(float f) {   // RNE fp32->bf16
    unsigned u = __float_as_uint(f);
    u += 0x7FFFu + ((u >> 16) & 1u);
    return (unsigned short)(u >> 16);
}

// ---------------------------------------------------------------------------
// prep_w: row-pair fused weight table, dx-major slot layout.
// Slot s = dy'*8 + dx, dy' in [0,8), dx in [0,8) (dx==7 -> zero column).
// For n = 8h + d (h = row half, d = out channel):
//   wtab[s][n][j] = W[(dy'-h)*7+dx][j][d] if 0<=dy'-h<7 && dx<7 else 0,
// W[tap][j][d] = sum_c kw[tap][j][c]*(c!=j)*sw[c][d]
// (7x7 conv fused with 1x1 k_scale; off-diagonal mask on (cin=j, cout=c)).
// Read as the MFMA *A* operand: lane field (l&15) indexes n = 8h+d.
// ---------------------------------------------------------------------------
__global__ __launch_bounds__(256)
void prep_w(const float* __restrict__ kw, const float* __restrict__ sw,
            unsigned short* __restrict__ wtab) {
    int it = blockIdx.x * 256 + threadIdx.x;      // (slot, j=cin)
    if (it >= NSLOT * 8) return;
    int s = it >> 3, j = it & 7;
    int dyp = s >> 3, dx = s & 7;
#pragma unroll
    for (int n = 0; n < 16; ++n) {
        int h = n >> 3, d = n & 7;
        int dy = dyp - h;
        float a = 0.f;
        if (dy >= 0 && dy < FIELD && dx < 7) {
            int tap = dy * 7 + dx;
#pragma unroll
            for (int c = 0; c < Cc; ++c) {
                float kv = (c == j) ? 0.f : kw[(tap * Cc + j) * Cc + c];
                a = fmaf(kv, sw[c * Cc + d], a);
            }
        }
        wtab[(s * 16 + n) * 8 + j] = f2bf(a);
    }
}

// ---------------------------------------------------------------------------
// init_qv: q0 = softmax(x) packed bf16x8; v = b - u@W  (u = min(lse-x, UCLIP))
// ---------------------------------------------------------------------------
__global__ __launch_bounds__(256)
void init_qv(const float* __restrict__ x, const float* __restrict__ sw,
             const float* __restrict__ sb,
             uint4* __restrict__ q0, float* __restrict__ v) {
    long long p = (long long)blockIdx.x * 256 + threadIdx.x;
    const float4* xp = (const float4*)(x + p * Cc);
    float4 a0 = xp[0], a1 = xp[1];
    float xv[Cc] = {a0.x, a0.y, a0.z, a0.w, a1.x, a1.y, a1.z, a1.w};
    float m = xv[0];
#pragma unroll
    for (int c = 1; c < Cc; ++c) m = fmaxf(m, xv[c]);
    float s = 0.f, e[Cc];
#pragma unroll
    for (int c = 0; c < Cc; ++c) { e[c] = __expf(xv[c] - m); s += e[c]; }
    float inv = 1.f / s;
    uint4 qo;
    qo.x = f2bf(e[0] * inv) | ((unsigned)f2bf(e[1] * inv) << 16);
    qo.y = f2bf(e[2] * inv) | ((unsigned)f2bf(e[3] * inv) << 16);
    qo.z = f2bf(e[4] * inv) | ((unsigned)f2bf(e[5] * inv) << 16);
    qo.w = f2bf(e[6] * inv) | ((unsigned)f2bf(e[7] * inv) << 16);
    q0[p] = qo;

    float lse = m + __logf(s);
    float u[Cc];
#pragma unroll
    for (int c = 0; c < Cc; ++c) u[c] = fminf(lse - xv[c], UCLIP);
    float vv[Cc];
#pragma unroll
    for (int d = 0; d < Cc; ++d) {
        float a = sb[d];
#pragma unroll
        for (int c = 0; c < Cc; ++c) a = fmaf(-u[c], sw[c * Cc + d], a);
        vv[d] = a;
    }
    float4* vp = (float4*)(v + p * Cc);
    vp[0] = make_float4(vv[0], vv[1], vv[2], vv[3]);
    vp[1] = make_float4(vv[4], vv[5], vv[6], vv[7]);
}

// ---------------------------------------------------------------------------
// mrf_iter: logits = v - conv7x7(q, k'); out = softmax(logits) bf16 (or
// logits fp32 on the last iteration).
// OPERAND-SWAPPED row-pair MFMA conv (mfma_f32_16x16x32_bf16), dx-major K:
//   A = weights (M = 16 = 2 rows x 8 ch), B = q pixels (N = 16 px),
//   K = 32 = 4 dx-consecutive slots x 8 cin; slot s = dy'*8 + (4*dxb + g).
// Per MFMA the wave reads ONE row, contiguous ~304B -> conflict-free (R0 law).
// Read dedup: row r0+dyp feeds acc0 (pair rows r0,r0+1; dy''=dyp<8) AND
// acc1 (pair rows r0+2,r0+3; dy''=dyp-2>=0) from the SAME register ->
// 20 ds_read_b128 / 32 MFMAs per wave.
// D: lane l holds D[4g+t][l&15]; one shfl_xor(16) per reg gives each lane a
// full 8-channel pixel: softmax in registers, no pen LDS, single barrier.
// Block = 512 thr = 8 waves; wave w: rows 4(w>>1).., col-half 16(w&1).
// ---------------------------------------------------------------------------
__global__ __launch_bounds__(512)
void mrf_iter(const uint4* __restrict__ qin,          // bf16x8 per pixel
              const unsigned short* __restrict__ wtab,
              const float* __restrict__ v,            // fp32, 8 per pixel
              uint4* __restrict__ qout,               // next q (bf16) if !last
              float* __restrict__ lout,               // logits fp32 if last
              int last) {
    __shared__ __align__(16) uint4 qs[HAH * QSTR];      // 22*39*16 = 13728 B

    const int tid = threadIdx.x;
    const int wv  = tid >> 6;        // wave 0..7
    const int l   = tid & 63;
    const int m   = l & 15;          // A-lane field (weight n) AND D col (pixel)
    const int g   = l >> 4;          // K-group (dx offset within quad)

    const int w0 = blockIdx.x * TW;
    const int h0 = blockIdx.y * TH;
    const int b  = blockIdx.z;

    const int r0 = 4 * (wv >> 1);    // wave's top output row
    const int cx = 16 * (wv & 1);    // wave's column half

    // --- this lane's output pixel (fixed): pair p=g&1, half h=g>>1 ---
    const int p   = g & 1;
    const int row = r0 + 2 * p + (g >> 1);
    const int px  = cx + m;
    const long long pix = ((long long)b * HH + (h0 + row)) * WW + (w0 + px);

    // --- hoisted v load for this pixel (latency hiding; block-private alias) ---
    const float4* vp = (const float4*)(v + pix * Cc);
    float4 v0 = vp[0], v1 = vp[1];

    // --- A fragments (weights): 16 x (8 bf16), L2-hot, VGPR-resident ---
    short8 bw[8][2];
#pragma unroll
    for (int dyq = 0; dyq < 8; ++dyq)
#pragma unroll
        for (int dxb = 0; dxb < 2; ++dxb) {
            int s = dyq * 8 + 4 * dxb + g;
            uint4 t = *(const uint4*)(wtab + (s * 16 + m) * 8);
            bw[dyq][dxb] = __builtin_bit_cast(short8, t);
        }

    // --- stage q tile + halo incl. pad col 38 (zero-pad = SAME) ---
    const uint4* qb = qin + (long long)b * HH * WW;
    for (int s = tid; s < HAH * QSTR; s += 512) {
        int sy = s / QSTR, sx = s - sy * QSTR;
        int gh = h0 + sy - PAD, gw = w0 + sx - PAD;
        uint4 val = make_uint4(0, 0, 0, 0);
        if (gh >= 0 && gh < HH && gw >= 0 && gw < WW)
            val = qb[(long long)gh * WW + gw];
        qs[s] = val;
    }
    __syncthreads();

    // --- K loop: 10 rows x 2 dx-blocks; each read feeds acc0 and/or acc1 ---
    f32x4 acc0 = (f32x4){0.f, 0.f, 0.f, 0.f};
    f32x4 acc1 = (f32x4){0.f, 0.f, 0.f, 0.f};
    const int colbase = cx + m + g;
#pragma unroll
    for (int dyp = 0; dyp < 10; ++dyp) {
        const int rb = (r0 + dyp) * QSTR + colbase;
#pragma unroll
        for (int dxb = 0; dxb < 2; ++dxb) {
            short8 qv = *(const short8*)&qs[rb + 4 * dxb];
            if (dyp < 8)
                acc0 = __builtin_amdgcn_mfma_f32_16x16x32_bf16(bw[dyp][dxb], qv, acc0, 0, 0, 0);
            if (dyp >= 2)
                acc1 = __builtin_amdgcn_mfma_f32_16x16x32_bf16(bw[dyp - 2][dxb], qv, acc1, 0, 0, 0);
        }
    }

    // --- in-register transpose: partner lane (l^16) has the other quad ---
    float o[Cc];
#pragma unroll
    for (int t = 0; t < 4; ++t) {
        float s0 = __shfl_xor(acc0[t], 16);
        float s1 = __shfl_xor(acc1[t], 16);
        o[t]     = p ? s1      : acc0[t];   // channels 0..3
        o[4 + t] = p ? acc1[t] : s0;        // channels 4..7
    }

    // --- epilogue (fully in registers) ---
    o[0] = v0.x - o[0]; o[1] = v0.y - o[1]; o[2] = v0.z - o[2]; o[3] = v0.w - o[3];
    o[4] = v1.x - o[4]; o[5] = v1.y - o[5]; o[6] = v1.z - o[6]; o[7] = v1.w - o[7];
    if (last) {
        float4* op = (float4*)(lout + pix * Cc);
        op[0] = make_float4(o[0], o[1], o[2], o[3]);
        op[1] = make_float4(o[4], o[5], o[6], o[7]);
    } else {
        float mm = o[0];
#pragma unroll
        for (int d = 1; d < Cc; ++d) mm = fmaxf(mm, o[d]);
        float ss = 0.f, e[Cc];
#pragma unroll
        for (int d = 0; d < Cc; ++d) { e[d] = __expf(o[d] - mm); ss += e[d]; }
        float inv = 1.f / ss;
        uint4 qo;
        qo.x = f2bf(e[0] * inv) | ((unsigned)f2bf(e[1] * inv) << 16);
        qo.y = f2bf(e[2] * inv) | ((unsigned)f2bf(e[3] * inv) << 16);
        qo.z = f2bf(e[4] * inv) | ((unsigned)f2bf(e[5] * inv) << 16);
        qo.w = f2bf(e[6] * inv) | ((unsigned)f2bf(e[7] * inv) << 16);
        qout[pix] = qo;
    }
}

extern "C" void kernel_launch(void* const* d_in, const int* in_sizes, int n_in,
                              void* d_out, int out_size, void* d_ws, size_t ws_size,
                              hipStream_t stream) {
    (void)in_sizes; (void)n_in; (void)out_size; (void)ws_size;
    const float* x  = (const float*)d_in[0];   // [32,384,384,8]
    const float* kw = (const float*)d_in[1];   // [7,7,8,8]
    const float* sw = (const float*)d_in[2];   // [8,8]
    const float* sb = (const float*)d_in[3];   // [8]

    const size_t QSZ = (size_t)BB * HH * WW * 16;        // 75,497,472 B (bf16x8)
    uint4* qA = (uint4*)d_ws;
    uint4* qB = (uint4*)((char*)d_ws + QSZ);
    unsigned short* wt = (unsigned short*)((char*)d_ws + 2 * QSZ);  // 16384 B
    float* vbuf = (float*)d_out;   // v lives in d_out; last iter overwrites in place

    prep_w<<<2, 256, 0, stream>>>(kw, sw, wt);

    const long long npix = (long long)BB * HH * WW;
    init_qv<<<(int)(npix / 256), 256, 0, stream>>>(x, sw, sb, qA, vbuf);

    dim3 grid(WW / TW, HH / TH, BB);   // 12 x 24 x 32
    mrf_iter<<<grid, 512, 0, stream>>>(qA, wt, vbuf, qB, nullptr, 0);
    mrf_iter<<<grid, 512, 0, stream>>>(qB, wt, vbuf, qA, nullptr, 0);
    mrf_iter<<<grid, 512, 0, stream>>>(qA, wt, vbuf, qB, nullptr, 0);
    mrf_iter<<<grid, 512, 0, stream>>>(qB, wt, vbuf, qA, nullptr, 0);
    mrf_iter<<<grid, 512, 0, stream>>>(qA, wt, vbuf, nullptr, (float*)d_out, 1);
}

// Round 7
// 461.139 us; speedup vs baseline: 1.3307x; 1.1440x over previous
//
#include <hip/hip_runtime.h>
#include <math.h>

#define Cc     8
#define FIELD  7
#define PAD    3
#define TW     32        // tile width
#define TH     16        // tile height
#define HAW    38        // TW + 6
#define HAH    22        // TH + 6
#define QSTR   39        // qs row stride (uint4); col 38 = pad col (staged, zero weight)
#define NSTG   (HAH*QSTR)  // 858 staged uint4 per tile
#define BB     32
#define HH     384
#define WW     384
#define NB     4         // batches per block (software-pipelined)
#define NSLOT  64        // 8 dy' x 8 dx slots (dx==7 zero-pad) for a row-PAIR
#define UCLIP  13.815510557964274f   // -log(1e-6)

typedef __attribute__((ext_vector_type(8))) short short8;  // 8 bf16 = 4 VGPRs
typedef __attribute__((ext_vector_type(4))) float f32x4;   // MFMA C/D

__device__ __forceinline__ unsigned short f2bf(float f) {   // RNE fp32->bf16
    unsigned u = __float_as_uint(f);
    u += 0x7FFFu + ((u >> 16) & 1u);
    return (unsigned short)(u >> 16);
}

// ---------------------------------------------------------------------------
// prep_w: row-pair fused weight table, dx-major slot layout (R6-verified).
// Slot s = dy'*8 + dx, dy' in [0,8), dx in [0,8) (dx==7 -> zero column).
// For n = 8h + d: wtab[s][n][j] = W[(dy'-h)*7+dx][j][d] if 0<=dy'-h<7 && dx<7
// else 0, W[tap][j][d] = sum_c kw[tap][j][c]*(c!=j)*sw[c][d].
// ---------------------------------------------------------------------------
__global__ __launch_bounds__(256)
void prep_w(const float* __restrict__ kw, const float* __restrict__ sw,
            unsigned short* __restrict__ wtab) {
    int it = blockIdx.x * 256 + threadIdx.x;      // (slot, j=cin)
    if (it >= NSLOT * 8) return;
    int s = it >> 3, j = it & 7;
    int dyp = s >> 3, dx = s & 7;
#pragma unroll
    for (int n = 0; n < 16; ++n) {
        int h = n >> 3, d = n & 7;
        int dy = dyp - h;
        float a = 0.f;
        if (dy >= 0 && dy < FIELD && dx < 7) {
            int tap = dy * 7 + dx;
#pragma unroll
            for (int c = 0; c < Cc; ++c) {
                float kv = (c == j) ? 0.f : kw[(tap * Cc + j) * Cc + c];
                a = fmaf(kv, sw[c * Cc + d], a);
            }
        }
        wtab[(s * 16 + n) * 8 + j] = f2bf(a);
    }
}

// ---------------------------------------------------------------------------
// init_qv: q0 = softmax(x) packed bf16x8; v = b - u@W  (u = min(lse-x, UCLIP))
// ---------------------------------------------------------------------------
__global__ __launch_bounds__(256)
void init_qv(const float* __restrict__ x, const float* __restrict__ sw,
             const float* __restrict__ sb,
             uint4* __restrict__ q0, float* __restrict__ v) {
    long long p = (long long)blockIdx.x * 256 + threadIdx.x;
    const float4* xp = (const float4*)(x + p * Cc);
    float4 a0 = xp[0], a1 = xp[1];
    float xv[Cc] = {a0.x, a0.y, a0.z, a0.w, a1.x, a1.y, a1.z, a1.w};
    float m = xv[0];
#pragma unroll
    for (int c = 1; c < Cc; ++c) m = fmaxf(m, xv[c]);
    float s = 0.f, e[Cc];
#pragma unroll
    for (int c = 0; c < Cc; ++c) { e[c] = __expf(xv[c] - m); s += e[c]; }
    float inv = 1.f / s;
    uint4 qo;
    qo.x = f2bf(e[0] * inv) | ((unsigned)f2bf(e[1] * inv) << 16);
    qo.y = f2bf(e[2] * inv) | ((unsigned)f2bf(e[3] * inv) << 16);
    qo.z = f2bf(e[4] * inv) | ((unsigned)f2bf(e[5] * inv) << 16);
    qo.w = f2bf(e[6] * inv) | ((unsigned)f2bf(e[7] * inv) << 16);
    q0[p] = qo;

    float lse = m + __logf(s);
    float u[Cc];
#pragma unroll
    for (int c = 0; c < Cc; ++c) u[c] = fminf(lse - xv[c], UCLIP);
    float vv[Cc];
#pragma unroll
    for (int d = 0; d < Cc; ++d) {
        float a = sb[d];
#pragma unroll
        for (int c = 0; c < Cc; ++c) a = fmaf(-u[c], sw[c * Cc + d], a);
        vv[d] = a;
    }
    float4* vp = (float4*)(v + p * Cc);
    vp[0] = make_float4(vv[0], vv[1], vv[2], vv[3]);
    vp[1] = make_float4(vv[4], vv[5], vv[6], vv[7]);
}

// ---------------------------------------------------------------------------
// mrf_iter: logits = v - conv7x7(q, k'); out = softmax(logits) bf16 (or
// logits fp32 on the last iteration).
// R6-verified math (operand-swapped row-pair MFMA, dx-major K, read-dedup,
// in-register softmax via shfl_xor(16), zero bank conflicts) + NEW schedule:
// each block pipelines NB=4 batches at one (x,y) tile through a double-
// buffered qs: global loads for tile t+1 issue BEFORE the K-loop of tile t
// (HBM latency hides under ~2000cy of compute), ds_write + one barrier after
// the epilogue. Weights load once per block (4x amortized).
// Block = 512 thr = 8 waves; wave w: rows 4(w>>1).., col-half 16(w&1).
// ---------------------------------------------------------------------------
__global__ __launch_bounds__(512)
void mrf_iter(const uint4* __restrict__ qin,          // bf16x8 per pixel
              const unsigned short* __restrict__ wtab,
              const float* __restrict__ v,            // fp32, 8 per pixel
              uint4* __restrict__ qout,               // next q (bf16) if !last
              float* __restrict__ lout,               // logits fp32 if last
              int last) {
    __shared__ __align__(16) uint4 qs[2][NSTG];         // 2 x 13728 B

    const int tid = threadIdx.x;
    const int wv  = tid >> 6;        // wave 0..7
    const int l   = tid & 63;
    const int m   = l & 15;          // A-lane field (weight n) AND D col (pixel)
    const int g   = l >> 4;          // K-group (dx offset within quad)

    const int w0 = blockIdx.x * TW;
    const int h0 = blockIdx.y * TH;
    const int b0 = blockIdx.z * NB;

    const int r0 = 4 * (wv >> 1);    // wave's top output row
    const int cx = 16 * (wv & 1);    // wave's column half

    // --- this lane's output pixel (batch-independent part) ---
    const int p   = g & 1;
    const int row = r0 + 2 * p + (g >> 1);
    const int px  = cx + m;
    const long long pixoff = (long long)(h0 + row) * WW + (w0 + px);
    const long long BSTR   = (long long)HH * WW;

    // --- A fragments (weights): 16 x (8 bf16), loaded ONCE per block ---
    short8 bw[8][2];
#pragma unroll
    for (int dyq = 0; dyq < 8; ++dyq)
#pragma unroll
        for (int dxb = 0; dxb < 2; ++dxb) {
            int s = dyq * 8 + 4 * dxb + g;
            uint4 t = *(const uint4*)(wtab + (s * 16 + m) * 8);
            bw[dyq][dxb] = __builtin_bit_cast(short8, t);
        }

    // --- staging geometry: this thread's 1-2 slots (batch-independent) ---
    const int sy0 = tid / QSTR, sx0 = tid - sy0 * QSTR;
    const int gh0 = h0 + sy0 - PAD, gw0 = w0 + sx0 - PAD;
    const bool in0 = (gh0 >= 0 && gh0 < HH && gw0 >= 0 && gw0 < WW);
    const long long off0 = (long long)gh0 * WW + gw0;
    const int  s1  = tid + 512;
    const bool has1 = (s1 < NSTG);
    const int sy1 = s1 / QSTR, sx1 = s1 - sy1 * QSTR;
    const int gh1 = h0 + sy1 - PAD, gw1 = w0 + sx1 - PAD;
    const bool in1 = has1 && (gh1 >= 0 && gh1 < HH && gw1 >= 0 && gw1 < WW);
    const long long off1 = (long long)gh1 * WW + gw1;

    const uint4* qb = qin + b0 * BSTR;
    const uint4  zz = make_uint4(0, 0, 0, 0);

    // --- prologue: stage tile 0, prefetch v(0) ---
    uint4 c0 = in0 ? qb[off0] : zz;
    uint4 c1 = in1 ? qb[off1] : zz;
    const float4* vp0 = (const float4*)(v + (b0 * BSTR + pixoff) * Cc);
    float4 v0 = vp0[0], v1 = vp0[1];
    qs[0][tid] = c0;
    if (has1) qs[0][s1] = c1;
    __syncthreads();

#pragma unroll
    for (int t = 0; t < NB; ++t) {
        // --- prefetch tile t+1 into registers (latency hides under K-loop) ---
        uint4 n0 = zz, n1 = zz;
        float4 vn0 = make_float4(0.f, 0.f, 0.f, 0.f), vn1 = vn0;
        if (t + 1 < NB) {
            const uint4* qbn = qb + (t + 1) * BSTR;
            n0 = in0 ? qbn[off0] : zz;
            n1 = in1 ? qbn[off1] : zz;
            const float4* vpn = (const float4*)(v + ((b0 + t + 1) * BSTR + pixoff) * Cc);
            vn0 = vpn[0]; vn1 = vpn[1];
        }

        // --- K loop on qs[t&1]: 10 rows x 2 dx-blocks, read-dedup'd ---
        f32x4 acc0 = (f32x4){0.f, 0.f, 0.f, 0.f};
        f32x4 acc1 = (f32x4){0.f, 0.f, 0.f, 0.f};
        const uint4* Q = qs[t & 1];
        const int colbase = cx + m + g;
#pragma unroll
        for (int dyp = 0; dyp < 10; ++dyp) {
            const int rb = (r0 + dyp) * QSTR + colbase;
#pragma unroll
            for (int dxb = 0; dxb < 2; ++dxb) {
                short8 qv = *(const short8*)&Q[rb + 4 * dxb];
                if (dyp < 8)
                    acc0 = __builtin_amdgcn_mfma_f32_16x16x32_bf16(bw[dyp][dxb], qv, acc0, 0, 0, 0);
                if (dyp >= 2)
                    acc1 = __builtin_amdgcn_mfma_f32_16x16x32_bf16(bw[dyp - 2][dxb], qv, acc1, 0, 0, 0);
            }
        }

        // --- in-register transpose: partner lane (l^16) has the other quad ---
        float o[Cc];
#pragma unroll
        for (int tt = 0; tt < 4; ++tt) {
            float s0v = __shfl_xor(acc0[tt], 16);
            float s1v = __shfl_xor(acc1[tt], 16);
            o[tt]     = p ? s1v      : acc0[tt];   // channels 0..3
            o[4 + tt] = p ? acc1[tt] : s0v;        // channels 4..7
        }

        // --- epilogue (in registers) for batch b0+t ---
        o[0] = v0.x - o[0]; o[1] = v0.y - o[1]; o[2] = v0.z - o[2]; o[3] = v0.w - o[3];
        o[4] = v1.x - o[4]; o[5] = v1.y - o[5]; o[6] = v1.z - o[6]; o[7] = v1.w - o[7];
        const long long pix = (b0 + t) * BSTR + pixoff;
        if (last) {
            float4* op = (float4*)(lout + pix * Cc);
            op[0] = make_float4(o[0], o[1], o[2], o[3]);
            op[1] = make_float4(o[4], o[5], o[6], o[7]);
        } else {
            float mm = o[0];
#pragma unroll
            for (int d = 1; d < Cc; ++d) mm = fmaxf(mm, o[d]);
            float ss = 0.f, e[Cc];
#pragma unroll
            for (int d = 0; d < Cc; ++d) { e[d] = __expf(o[d] - mm); ss += e[d]; }
            float inv = 1.f / ss;
            uint4 qo;
            qo.x = f2bf(e[0] * inv) | ((unsigned)f2bf(e[1] * inv) << 16);
            qo.y = f2bf(e[2] * inv) | ((unsigned)f2bf(e[3] * inv) << 16);
            qo.z = f2bf(e[4] * inv) | ((unsigned)f2bf(e[5] * inv) << 16);
            qo.w = f2bf(e[6] * inv) | ((unsigned)f2bf(e[7] * inv) << 16);
            qout[pix] = qo;
        }

        // --- commit prefetched tile t+1 to the other buffer ---
        if (t + 1 < NB) {
            qs[(t + 1) & 1][tid] = n0;
            if (has1) qs[(t + 1) & 1][s1] = n1;
            __syncthreads();
            v0 = vn0; v1 = vn1;
        }
    }
}

extern "C" void kernel_launch(void* const* d_in, const int* in_sizes, int n_in,
                              void* d_out, int out_size, void* d_ws, size_t ws_size,
                              hipStream_t stream) {
    (void)in_sizes; (void)n_in; (void)out_size; (void)ws_size;
    const float* x  = (const float*)d_in[0];   // [32,384,384,8]
    const float* kw = (const float*)d_in[1];   // [7,7,8,8]
    const float* sw = (const float*)d_in[2];   // [8,8]
    const float* sb = (const float*)d_in[3];   // [8]

    const size_t QSZ = (size_t)BB * HH * WW * 16;        // 75,497,472 B (bf16x8)
    uint4* qA = (uint4*)d_ws;
    uint4* qB = (uint4*)((char*)d_ws + QSZ);
    unsigned short* wt = (unsigned short*)((char*)d_ws + 2 * QSZ);  // 16384 B
    float* vbuf = (float*)d_out;   // v lives in d_out; last iter overwrites in place

    prep_w<<<2, 256, 0, stream>>>(kw, sw, wt);

    const long long npix = (long long)BB * HH * WW;
    init_qv<<<(int)(npix / 256), 256, 0, stream>>>(x, sw, sb, qA, vbuf);

    dim3 grid(WW / TW, HH / TH, BB / NB);   // 12 x 24 x 8
    mrf_iter<<<grid, 512, 0, stream>>>(qA, wt, vbuf, qB, nullptr, 0);
    mrf_iter<<<grid, 512, 0, stream>>>(qB, wt, vbuf, qA, nullptr, 0);
    mrf_iter<<<grid, 512, 0, stream>>>(qA, wt, vbuf, qB, nullptr, 0);
    mrf_iter<<<grid, 512, 0, stream>>>(qB, wt, vbuf, qA, nullptr, 0);
    mrf_iter<<<grid, 512, 0, stream>>>(qA, wt, vbuf, nullptr, (float*)d_out, 1);
}

// Round 8
// 359.129 us; speedup vs baseline: 1.7086x; 1.2841x over previous
//
#include <hip/hip_runtime.h>
#include <math.h>

#define Cc     8
#define FIELD  7
#define PAD    3
#define TW     32        // tile width
#define TH     16        // tile height
#define HAW    38        // TW + 6
#define HAH    22        // TH + 6
#define QSTR   39        // qs row stride (uint4); col 38 = pad col (staged, zero weight)
#define NSTG   (HAH*QSTR)  // 858 staged uint4 per tile
#define BB     32
#define HH     384
#define WW     384
#define NB     4         // batches per block (software-pipelined)
#define NSLOT  64        // 8 dy' x 8 dx slots (dx==7 zero-pad) for a row-PAIR
#define UCLIP  13.815510557964274f   // -log(1e-6)

typedef __attribute__((ext_vector_type(8))) short short8;  // 8 bf16 = 4 VGPRs
typedef __attribute__((ext_vector_type(4))) float f32x4;   // MFMA C/D

__device__ __forceinline__ unsigned short f2bf(float f) {   // RNE fp32->bf16
    unsigned u = __float_as_uint(f);
    u += 0x7FFFu + ((u >> 16) & 1u);
    return (unsigned short)(u >> 16);
}
__device__ __forceinline__ unsigned short f2h(float f) {    // RNE fp32->fp16
    return __builtin_bit_cast(unsigned short, (_Float16)f);
}
__device__ __forceinline__ float hlo(unsigned u) {
    return (float)__builtin_bit_cast(_Float16, (unsigned short)(u & 0xFFFFu));
}
__device__ __forceinline__ float hhi(unsigned u) {
    return (float)__builtin_bit_cast(_Float16, (unsigned short)(u >> 16));
}

// ---------------------------------------------------------------------------
// prep_w: row-pair fused weight table, dx-major slot layout (R6/R7-verified).
// Slot s = dy'*8 + dx, dy' in [0,8), dx in [0,8) (dx==7 -> zero column).
// For n = 8h + d: wtab[s][n][j] = W[(dy'-h)*7+dx][j][d] if 0<=dy'-h<7 && dx<7
// else 0, W[tap][j][d] = sum_c kw[tap][j][c]*(c!=j)*sw[c][d].
// ---------------------------------------------------------------------------
__global__ __launch_bounds__(256)
void prep_w(const float* __restrict__ kw, const float* __restrict__ sw,
            unsigned short* __restrict__ wtab) {
    int it = blockIdx.x * 256 + threadIdx.x;      // (slot, j=cin)
    if (it >= NSLOT * 8) return;
    int s = it >> 3, j = it & 7;
    int dyp = s >> 3, dx = s & 7;
#pragma unroll
    for (int n = 0; n < 16; ++n) {
        int h = n >> 3, d = n & 7;
        int dy = dyp - h;
        float a = 0.f;
        if (dy >= 0 && dy < FIELD && dx < 7) {
            int tap = dy * 7 + dx;
#pragma unroll
            for (int c = 0; c < Cc; ++c) {
                float kv = (c == j) ? 0.f : kw[(tap * Cc + j) * Cc + c];
                a = fmaf(kv, sw[c * Cc + d], a);
            }
        }
        wtab[(s * 16 + n) * 8 + j] = f2bf(a);
    }
}

// ---------------------------------------------------------------------------
// init_qv: q0 = softmax(x) packed bf16x8; v = b - u@W  (u = min(lse-x, UCLIP)).
// v stored fp16 (vh, 16B/px) when half!=0, else fp32 (vf, 32B/px).
// ---------------------------------------------------------------------------
__global__ __launch_bounds__(256)
void init_qv(const float* __restrict__ x, const float* __restrict__ sw,
             const float* __restrict__ sb,
             uint4* __restrict__ q0, float* __restrict__ vf,
             uint4* __restrict__ vh, int half) {
    long long p = (long long)blockIdx.x * 256 + threadIdx.x;
    const float4* xp = (const float4*)(x + p * Cc);
    float4 a0 = xp[0], a1 = xp[1];
    float xv[Cc] = {a0.x, a0.y, a0.z, a0.w, a1.x, a1.y, a1.z, a1.w};
    float m = xv[0];
#pragma unroll
    for (int c = 1; c < Cc; ++c) m = fmaxf(m, xv[c]);
    float s = 0.f, e[Cc];
#pragma unroll
    for (int c = 0; c < Cc; ++c) { e[c] = __expf(xv[c] - m); s += e[c]; }
    float inv = 1.f / s;
    uint4 qo;
    qo.x = f2bf(e[0] * inv) | ((unsigned)f2bf(e[1] * inv) << 16);
    qo.y = f2bf(e[2] * inv) | ((unsigned)f2bf(e[3] * inv) << 16);
    qo.z = f2bf(e[4] * inv) | ((unsigned)f2bf(e[5] * inv) << 16);
    qo.w = f2bf(e[6] * inv) | ((unsigned)f2bf(e[7] * inv) << 16);
    q0[p] = qo;

    float lse = m + __logf(s);
    float u[Cc];
#pragma unroll
    for (int c = 0; c < Cc; ++c) u[c] = fminf(lse - xv[c], UCLIP);
    float vv[Cc];
#pragma unroll
    for (int d = 0; d < Cc; ++d) {
        float a = sb[d];
#pragma unroll
        for (int c = 0; c < Cc; ++c) a = fmaf(-u[c], sw[c * Cc + d], a);
        vv[d] = a;
    }
    if (half) {
        uint4 vo;
        vo.x = f2h(vv[0]) | ((unsigned)f2h(vv[1]) << 16);
        vo.y = f2h(vv[2]) | ((unsigned)f2h(vv[3]) << 16);
        vo.z = f2h(vv[4]) | ((unsigned)f2h(vv[5]) << 16);
        vo.w = f2h(vv[6]) | ((unsigned)f2h(vv[7]) << 16);
        vh[p] = vo;
    } else {
        float4* vp = (float4*)(vf + p * Cc);
        vp[0] = make_float4(vv[0], vv[1], vv[2], vv[3]);
        vp[1] = make_float4(vv[4], vv[5], vv[6], vv[7]);
    }
}

// ---------------------------------------------------------------------------
// mrf_iter: logits = v - conv7x7(q, k'); out = softmax(logits) bf16 (or
// logits fp32 on the last iteration).
// R7-verified schedule: NB=4 batch pipeline on double-buffered qs, operand-
// swapped row-pair MFMA (dx-major K, read-dedup, 0 bank conflicts), in-reg
// softmax via shfl_xor(16), single barrier per tile.
// VHALF=1: v is fp16 (16B/px) -> per-iter traffic 226.5 MB, working set
// {qA,qB,v} = 226.5 MB < 256 MB L3 -> iterations run Infinity-Cache-resident.
// ---------------------------------------------------------------------------
template<int VHALF>
__global__ __launch_bounds__(512)
void mrf_iter(const uint4* __restrict__ qin,          // bf16x8 per pixel
              const unsigned short* __restrict__ wtab,
              const void* __restrict__ vsrc,          // fp16 or fp32, 8 per px
              uint4* __restrict__ qout,               // next q (bf16) if !last
              float* __restrict__ lout,               // logits fp32 if last
              int last) {
    __shared__ __align__(16) uint4 qs[2][NSTG];         // 2 x 13728 B

    const int tid = threadIdx.x;
    const int wv  = tid >> 6;        // wave 0..7
    const int l   = tid & 63;
    const int m   = l & 15;          // A-lane field (weight n) AND D col (pixel)
    const int g   = l >> 4;          // K-group (dx offset within quad)

    const int w0 = blockIdx.x * TW;
    const int h0 = blockIdx.y * TH;
    const int b0 = blockIdx.z * NB;

    const int r0 = 4 * (wv >> 1);    // wave's top output row
    const int cx = 16 * (wv & 1);    // wave's column half

    // --- this lane's output pixel (batch-independent part) ---
    const int p   = g & 1;
    const int row = r0 + 2 * p + (g >> 1);
    const int px  = cx + m;
    const long long pixoff = (long long)(h0 + row) * WW + (w0 + px);
    const long long BSTR   = (long long)HH * WW;

    // --- A fragments (weights): 16 x (8 bf16), loaded ONCE per block ---
    short8 bw[8][2];
#pragma unroll
    for (int dyq = 0; dyq < 8; ++dyq)
#pragma unroll
        for (int dxb = 0; dxb < 2; ++dxb) {
            int s = dyq * 8 + 4 * dxb + g;
            uint4 t = *(const uint4*)(wtab + (s * 16 + m) * 8);
            bw[dyq][dxb] = __builtin_bit_cast(short8, t);
        }

    // --- staging geometry: this thread's 1-2 slots (batch-independent) ---
    const int sy0 = tid / QSTR, sx0 = tid - sy0 * QSTR;
    const int gh0 = h0 + sy0 - PAD, gw0 = w0 + sx0 - PAD;
    const bool in0 = (gh0 >= 0 && gh0 < HH && gw0 >= 0 && gw0 < WW);
    const long long off0 = (long long)gh0 * WW + gw0;
    const int  s1  = tid + 512;
    const bool has1 = (s1 < NSTG);
    const int sy1 = s1 / QSTR, sx1 = s1 - sy1 * QSTR;
    const int gh1 = h0 + sy1 - PAD, gw1 = w0 + sx1 - PAD;
    const bool in1 = has1 && (gh1 >= 0 && gh1 < HH && gw1 >= 0 && gw1 < WW);
    const long long off1 = (long long)gh1 * WW + gw1;

    const uint4* qb = qin + b0 * BSTR;
    const uint4  zz = make_uint4(0, 0, 0, 0);

    // --- prologue: stage tile 0, prefetch v(0) ---
    uint4 c0 = in0 ? qb[off0] : zz;
    uint4 c1 = in1 ? qb[off1] : zz;
    uint4  vhv = zz;
    float4 v0, v1;
    if constexpr (VHALF) {
        vhv = ((const uint4*)vsrc)[b0 * BSTR + pixoff];
    } else {
        const float4* vp0 = (const float4*)((const float*)vsrc + (b0 * BSTR + pixoff) * Cc);
        v0 = vp0[0]; v1 = vp0[1];
    }
    qs[0][tid] = c0;
    if (has1) qs[0][s1] = c1;
    __syncthreads();

#pragma unroll
    for (int t = 0; t < NB; ++t) {
        // --- prefetch tile t+1 into registers (latency hides under K-loop) ---
        uint4 n0 = zz, n1 = zz, vhn = zz;
        float4 vn0 = make_float4(0.f, 0.f, 0.f, 0.f), vn1 = vn0;
        if (t + 1 < NB) {
            const uint4* qbn = qb + (t + 1) * BSTR;
            n0 = in0 ? qbn[off0] : zz;
            n1 = in1 ? qbn[off1] : zz;
            if constexpr (VHALF) {
                vhn = ((const uint4*)vsrc)[(b0 + t + 1) * BSTR + pixoff];
            } else {
                const float4* vpn = (const float4*)((const float*)vsrc + ((b0 + t + 1) * BSTR + pixoff) * Cc);
                vn0 = vpn[0]; vn1 = vpn[1];
            }
        }

        // --- K loop on qs[t&1]: 10 rows x 2 dx-blocks, read-dedup'd ---
        f32x4 acc0 = (f32x4){0.f, 0.f, 0.f, 0.f};
        f32x4 acc1 = (f32x4){0.f, 0.f, 0.f, 0.f};
        const uint4* Q = qs[t & 1];
        const int colbase = cx + m + g;
#pragma unroll
        for (int dyp = 0; dyp < 10; ++dyp) {
            const int rb = (r0 + dyp) * QSTR + colbase;
#pragma unroll
            for (int dxb = 0; dxb < 2; ++dxb) {
                short8 qv = *(const short8*)&Q[rb + 4 * dxb];
                if (dyp < 8)
                    acc0 = __builtin_amdgcn_mfma_f32_16x16x32_bf16(bw[dyp][dxb], qv, acc0, 0, 0, 0);
                if (dyp >= 2)
                    acc1 = __builtin_amdgcn_mfma_f32_16x16x32_bf16(bw[dyp - 2][dxb], qv, acc1, 0, 0, 0);
            }
        }

        // --- in-register transpose: partner lane (l^16) has the other quad ---
        float o[Cc];
#pragma unroll
        for (int tt = 0; tt < 4; ++tt) {
            float s0v = __shfl_xor(acc0[tt], 16);
            float s1v = __shfl_xor(acc1[tt], 16);
            o[tt]     = p ? s1v      : acc0[tt];   // channels 0..3
            o[4 + tt] = p ? acc1[tt] : s0v;        // channels 4..7
        }

        // --- epilogue (in registers) for batch b0+t ---
        float vv[Cc];
        if constexpr (VHALF) {
            vv[0] = hlo(vhv.x); vv[1] = hhi(vhv.x);
            vv[2] = hlo(vhv.y); vv[3] = hhi(vhv.y);
            vv[4] = hlo(vhv.z); vv[5] = hhi(vhv.z);
            vv[6] = hlo(vhv.w); vv[7] = hhi(vhv.w);
        } else {
            vv[0] = v0.x; vv[1] = v0.y; vv[2] = v0.z; vv[3] = v0.w;
            vv[4] = v1.x; vv[5] = v1.y; vv[6] = v1.z; vv[7] = v1.w;
        }
#pragma unroll
        for (int d = 0; d < Cc; ++d) o[d] = vv[d] - o[d];
        const long long pix = (b0 + t) * BSTR + pixoff;
        if (last) {
            float4* op = (float4*)(lout + pix * Cc);
            op[0] = make_float4(o[0], o[1], o[2], o[3]);
            op[1] = make_float4(o[4], o[5], o[6], o[7]);
        } else {
            float mm = o[0];
#pragma unroll
            for (int d = 1; d < Cc; ++d) mm = fmaxf(mm, o[d]);
            float ss = 0.f, e[Cc];
#pragma unroll
            for (int d = 0; d < Cc; ++d) { e[d] = __expf(o[d] - mm); ss += e[d]; }
            float inv = 1.f / ss;
            uint4 qo;
            qo.x = f2bf(e[0] * inv) | ((unsigned)f2bf(e[1] * inv) << 16);
            qo.y = f2bf(e[2] * inv) | ((unsigned)f2bf(e[3] * inv) << 16);
            qo.z = f2bf(e[4] * inv) | ((unsigned)f2bf(e[5] * inv) << 16);
            qo.w = f2bf(e[6] * inv) | ((unsigned)f2bf(e[7] * inv) << 16);
            qout[pix] = qo;
        }

        // --- commit prefetched tile t+1 to the other buffer ---
        if (t + 1 < NB) {
            qs[(t + 1) & 1][tid] = n0;
            if (has1) qs[(t + 1) & 1][s1] = n1;
            __syncthreads();
            if constexpr (VHALF) { vhv = vhn; } else { v0 = vn0; v1 = vn1; }
        }
    }
}

extern "C" void kernel_launch(void* const* d_in, const int* in_sizes, int n_in,
                              void* d_out, int out_size, void* d_ws, size_t ws_size,
                              hipStream_t stream) {
    (void)in_sizes; (void)n_in; (void)out_size;
    const float* x  = (const float*)d_in[0];   // [32,384,384,8]
    const float* kw = (const float*)d_in[1];   // [7,7,8,8]
    const float* sw = (const float*)d_in[2];   // [8,8]
    const float* sb = (const float*)d_in[3];   // [8]

    const size_t QSZ = (size_t)BB * HH * WW * 16;   // 75,497,472 B (bf16x8)
    const size_t VSZ = (size_t)BB * HH * WW * 16;   // 75,497,472 B (fp16x8)
    uint4* qA = (uint4*)d_ws;
    uint4* qB = (uint4*)((char*)d_ws + QSZ);

    const long long npix = (long long)BB * HH * WW;
    dim3 grid(WW / TW, HH / TH, BB / NB);   // 12 x 24 x 8

    if (ws_size >= 2 * QSZ + VSZ + 16384) {
        // fp16-v path: whole iteration working set {qA,qB,v} = 226.5 MB < L3
        uint4* vh = (uint4*)((char*)d_ws + 2 * QSZ);
        unsigned short* wt = (unsigned short*)((char*)d_ws + 2 * QSZ + VSZ);
        prep_w<<<2, 256, 0, stream>>>(kw, sw, wt);
        init_qv<<<(int)(npix / 256), 256, 0, stream>>>(x, sw, sb, qA, nullptr, vh, 1);
        mrf_iter<1><<<grid, 512, 0, stream>>>(qA, wt, vh, qB, nullptr, 0);
        mrf_iter<1><<<grid, 512, 0, stream>>>(qB, wt, vh, qA, nullptr, 0);
        mrf_iter<1><<<grid, 512, 0, stream>>>(qA, wt, vh, qB, nullptr, 0);
        mrf_iter<1><<<grid, 512, 0, stream>>>(qB, wt, vh, qA, nullptr, 0);
        mrf_iter<1><<<grid, 512, 0, stream>>>(qA, wt, vh, nullptr, (float*)d_out, 1);
    } else {
        // fallback: exact R7-verified fp32-v-in-d_out path
        float* vbuf = (float*)d_out;
        unsigned short* wt = (unsigned short*)((char*)d_ws + 2 * QSZ);
        prep_w<<<2, 256, 0, stream>>>(kw, sw, wt);
        init_qv<<<(int)(npix / 256), 256, 0, stream>>>(x, sw, sb, qA, vbuf, nullptr, 0);
        mrf_iter<0><<<grid, 512, 0, stream>>>(qA, wt, vbuf, qB, nullptr, 0);
        mrf_iter<0><<<grid, 512, 0, stream>>>(qB, wt, vbuf, qA, nullptr, 0);
        mrf_iter<0><<<grid, 512, 0, stream>>>(qA, wt, vbuf, qB, nullptr, 0);
        mrf_iter<0><<<grid, 512, 0, stream>>>(qB, wt, vbuf, qA, nullptr, 0);
        mrf_iter<0><<<grid, 512, 0, stream>>>(qA, wt, vbuf, nullptr, (float*)d_out, 1);
    }
}